// Round 2
// baseline (84.617 us; speedup 1.0000x reference)
//
#include <hip/hip_runtime.h>

using short8 = __attribute__((ext_vector_type(8))) short;
using f32x4  = __attribute__((ext_vector_type(4))) float;
using u32x4  = __attribute__((ext_vector_type(4))) unsigned int;

#define NC 256
#define NW 64
#define H2 24
#define ND 21
#define HW 3072              /* 48*64, per-channel stride in floats */

__device__ __forceinline__ int imax(int a, int b) { return a > b ? a : b; }
__device__ __forceinline__ int imin(int a, int b) { return a < b ? a : b; }

// single-instruction RNE pack: dst.lo = bf16(a), dst.hi = bf16(b)
__device__ __forceinline__ unsigned int cvtpk(float a, float b) {
    unsigned int r;
    asm("v_cvt_pk_bf16_f32 %0, %1, %2" : "=v"(r) : "v"(a), "v"(b));
    return r;
}

// byte offset into a [64 rows][256 ch] bf16 LDS tile, XOR-swizzled so lanes
// reading different rows at the same channel range spread across banks
__device__ __forceinline__ unsigned int swz_off(int row, int cb) {
    return (row << 9) + ((cb << 1) ^ (((row >> 1) & 7) << 4));
}

// barrier that drains LDS ops only — global prefetch loads stay in flight
#define BARRIER() asm volatile("s_waitcnt lgkmcnt(0)\n\ts_barrier" ::: "memory")

struct Stage { float2 v[16]; };   // one staged row slice: 128 B/thread

__device__ __forceinline__ void stage_issue(Stage& st, const float* rowbase, int xp, int cg) {
    const float* s = rowbase + 2 * xp;
    #pragma unroll
    for (int cc = 0; cc < 2; ++cc)
        #pragma unroll
        for (int e = 0; e < 4; ++e) {
            int c = cc * 128 + cg * 8 + 2 * e;
            st.v[cc * 8 + 2 * e    ] = *reinterpret_cast<const float2*>(s + (size_t)c * HW);
            st.v[cc * 8 + 2 * e + 1] = *reinterpret_cast<const float2*>(s + (size_t)(c + 1) * HW);
        }
}

__device__ __forceinline__ void stage_commit(const Stage& st, unsigned short* lds, int xp, int cg) {
    #pragma unroll
    for (int cc = 0; cc < 2; ++cc) {
        int c0 = cc * 128 + cg * 8;
        u32x4 p0, p1;
        #pragma unroll
        for (int e = 0; e < 4; ++e) {
            float2 va = st.v[cc * 8 + 2 * e];
            float2 vb = st.v[cc * 8 + 2 * e + 1];
            p0[e] = cvtpk(va.x, vb.x);   // low = even channel (matches verified layout)
            p1[e] = cvtpk(va.y, vb.y);
        }
        *reinterpret_cast<u32x4*>(reinterpret_cast<char*>(lds) + swz_off(2 * xp,     c0)) = p0;
        *reinterpret_cast<u32x4*>(reinterpret_cast<char*>(lds) + swz_off(2 * xp + 1, c0)) = p1;
    }
}

__global__ __launch_bounds__(512, 6) void corr_kernel(const float* __restrict__ f1,
                                                      const float* __restrict__ f2,
                                                      float* __restrict__ out) {
    // A is staged into Blds first, fragments hoisted to VGPRs, then Blds is
    // reused as the (single, reg-double-buffered) B row buffer.  41 KB total
    // -> 3 WGs/CU resident, 768 WGs = exactly one dispatch round.
    __shared__ __align__(16) unsigned short Blds[64 * 256];
    __shared__ float Slds[64][33];

    int bid = blockIdx.x;
    // bijective XCD swizzle: 768 = 8 * 96; one XCD chunk = 2 (b,py) groups,
    // consecutive swz = same uy half-pair -> f1/f2 row re-reads are L2-local
    int swz = (bid & 7) * 96 + (bid >> 3);
    int hf  = swz & 1;                 // which half of the 21 displacement rows
    int uy  = (swz >> 1) % 24;
    int g   = swz / 48;                // b*2 + py
    int py  = g & 1;
    int b   = g >> 1;
    int y   = 2 * uy + py;

    int tid  = threadIdx.x;
    int lane = tid & 63;
    int w    = tid >> 6;
    int xp   = tid & 31;
    int cg   = tid >> 5;

    const float* f1row  = f1 + (size_t)b * NC * HW + (size_t)y * NW;
    const float* f2base = f2 + (size_t)b * NC * HW;
    float* outb = out + (size_t)b * 441 * HW + (size_t)y * NW;   // + d*HW + x

    // this half's displacement-row range: i in [ilo_h, ihi_h], vy = uy + i - 10
    int ilo_h = hf ? 11 : 0;
    int ihi_h = hf ? 20 : 10;
    int ilo   = imax(ilo_h, 10 - uy);      // first i with valid vy
    int ihi   = imin(ihi_h, 33 - uy);      // last i with valid vy

    // zero-fill output rows whose displaced source row is out of bounds
    for (int i = ilo_h; i <= ihi_h; ++i) {
        if (i >= ilo && i <= ihi) continue;
        for (int t = tid; t < ND * 64; t += 512) {
            int j = t >> 6, x = t & 63;
            outb[(size_t)(i * ND + j) * HW + x] = 0.f;
        }
    }

    if (ilo > ihi) return;   // uniform: nothing but zero-fill for this WG

    // ---- prologue: stage A into Blds, hoist fragments ----
    Stage st;
    stage_issue(st, f1row, xp, cg);
    stage_commit(st, Blds, xp, cg);
    BARRIER();

    int px  = w & 1;
    int m0  = ((w >> 1) & 1) * 16;
    int n0  = ((w >> 2) & 1) * 16;
    int l15 = lane & 15;
    int kgr = (lane >> 4) * 8;

    short8 afrag[8];
    int arow = 2 * (m0 + l15) + px;
    #pragma unroll
    for (int kk = 0; kk < 8; ++kk)
        afrag[kk] = *reinterpret_cast<const short8*>(
            reinterpret_cast<const char*>(Blds) + swz_off(arow, kk * 32 + kgr));

    int brow = 2 * (n0 + l15) + px;
    int srow = 2 * (m0 + (lane >> 4) * 4) + px;
    int scol = n0 + l15;

    // prefetch first B row into registers
    stage_issue(st, f2base + (size_t)(2 * (uy + ilo - 10) + py) * NW, xp, cg);

    for (int i = ilo; i <= ihi; ++i) {
        BARRIER();   // (a) all prior LDS reads (afrag hoist / B frags / gather) retired
        stage_commit(st, Blds, xp, cg);
        if (i < ihi)   // prefetch next row; hides under MFMA + gather below
            stage_issue(st, f2base + (size_t)(2 * (uy + i + 1 - 10) + py) * NW, xp, cg);
        BARRIER();   // (b) B row ready in LDS

        f32x4 acc = {0.f, 0.f, 0.f, 0.f};
        #pragma unroll
        for (int kk = 0; kk < 8; ++kk) {
            short8 bfrag = *reinterpret_cast<const short8*>(
                reinterpret_cast<const char*>(Blds) + swz_off(brow, kk * 32 + kgr));
            acc = __builtin_amdgcn_mfma_f32_16x16x32_bf16(afrag[kk], bfrag, acc, 0, 0, 0);
        }

        // C/D layout: col = lane&15 (-> vx), row = (lane>>4)*4 + r (-> ux)
        #pragma unroll
        for (int r = 0; r < 4; ++r)
            Slds[srow + 2 * r][scol] = acc[r] * (1.f / 256.f);
        BARRIER();   // (c) S ready

        // banded gather: out[ux, j] = S[ux, ux + j - 10]; coalesced 256 B stores
        for (int t = tid; t < ND * 64; t += 512) {
            int j = t >> 6, x = t & 63;
            int vx = (x >> 1) + j - 10;
            float v = ((unsigned)vx < 32u) ? Slds[x][vx] : 0.f;
            outb[(size_t)(i * ND + j) * HW + x] = v;
        }
    }
}

extern "C" void kernel_launch(void* const* d_in, const int* in_sizes, int n_in,
                              void* d_out, int out_size, void* d_ws, size_t ws_size,
                              hipStream_t stream) {
    const float* in1 = (const float*)d_in[0];
    const float* in2 = (const float*)d_in[1];
    float* o = (float*)d_out;
    hipLaunchKernelGGL(corr_kernel, dim3(768), dim3(512), 0, stream, in1, in2, o);
}

// Round 3
// 44.795 us; speedup vs baseline: 1.8890x; 1.8890x over previous
//
#include <hip/hip_runtime.h>

using short8 = __attribute__((ext_vector_type(8))) short;
using f32x4  = __attribute__((ext_vector_type(4))) float;
using u32x4  = __attribute__((ext_vector_type(4))) unsigned int;

#define NC 256
#define NW 64
#define ND 21
#define HW 3072              /* 48*64, per-channel stride in floats */

static const size_t WS_NEEDED = (size_t)8 * 48 * 32 * 1024;   /* 12.58 MB of bf16 blobs */

__device__ __forceinline__ int imax(int a, int b) { return a > b ? a : b; }
__device__ __forceinline__ int imin(int a, int b) { return a < b ? a : b; }

// single-instruction RNE pack: dst.lo = bf16(a), dst.hi = bf16(b)
__device__ __forceinline__ unsigned int cvtpk(float a, float b) {
    unsigned int r;
    asm("v_cvt_pk_bf16_f32 %0, %1, %2" : "=v"(r) : "v"(a), "v"(b));
    return r;
}

// byte offset into a [64 rows][256 ch] bf16 tile, XOR-swizzled so lanes
// reading different rows at the same channel range spread across banks
__device__ __forceinline__ unsigned int swz_off(int row, int cb) {
    return (row << 9) + ((cb << 1) ^ (((row >> 1) & 7) << 4));
}

// barrier draining LDS ops only — global loads stay in flight
#define BARRIER() asm volatile("s_waitcnt lgkmcnt(0)\n\ts_barrier" ::: "memory")

struct Stage { float2 v[16]; };   // one f32 row slice: 128 B/thread

__device__ __forceinline__ void stage_issue(Stage& st, const float* rowbase, int xp, int cg) {
    const float* s = rowbase + 2 * xp;
    #pragma unroll
    for (int cc = 0; cc < 2; ++cc)
        #pragma unroll
        for (int e = 0; e < 4; ++e) {
            int c = cc * 128 + cg * 8 + 2 * e;
            st.v[cc * 8 + 2 * e    ] = *reinterpret_cast<const float2*>(s + (size_t)c * HW);
            st.v[cc * 8 + 2 * e + 1] = *reinterpret_cast<const float2*>(s + (size_t)(c + 1) * HW);
        }
}

// pack one cc-half of the stage into two u32x4 (bf16 pairs, transposed layout)
__device__ __forceinline__ void stage_pack(const Stage& st, int cc, u32x4& p0, u32x4& p1) {
    #pragma unroll
    for (int e = 0; e < 4; ++e) {
        float2 va = st.v[cc * 8 + 2 * e];
        float2 vb = st.v[cc * 8 + 2 * e + 1];
        p0[e] = cvtpk(va.x, vb.x);
        p1[e] = cvtpk(va.y, vb.y);
    }
}

__device__ __forceinline__ void stage_commit_lds(const Stage& st, unsigned short* lds, int xp, int cg) {
    #pragma unroll
    for (int cc = 0; cc < 2; ++cc) {
        int c0 = cc * 128 + cg * 8;
        u32x4 p0, p1;
        stage_pack(st, cc, p0, p1);
        *reinterpret_cast<u32x4*>(reinterpret_cast<char*>(lds) + swz_off(2 * xp,     c0)) = p0;
        *reinterpret_cast<u32x4*>(reinterpret_cast<char*>(lds) + swz_off(2 * xp + 1, c0)) = p1;
    }
}

__device__ __forceinline__ void stage_commit_glob(const Stage& st, unsigned short* blob, int xp, int cg) {
    #pragma unroll
    for (int cc = 0; cc < 2; ++cc) {
        int c0 = cc * 128 + cg * 8;
        u32x4 p0, p1;
        stage_pack(st, cc, p0, p1);
        *reinterpret_cast<u32x4*>(reinterpret_cast<char*>(blob) + swz_off(2 * xp,     c0)) = p0;
        *reinterpret_cast<u32x4*>(reinterpret_cast<char*>(blob) + swz_off(2 * xp + 1, c0)) = p1;
    }
}

// ---------------- pre-pass: f2 (f32, [c][x]) -> ws blobs (bf16, [x][c] swizzled) ----------------
__global__ __launch_bounds__(512, 4) void prep_kernel(const float* __restrict__ f2,
                                                      unsigned short* __restrict__ ws) {
    int bid = blockIdx.x;                 // b*48 + y
    int b = bid / 48, y = bid - b * 48;
    const float* row = f2 + (size_t)b * NC * HW + (size_t)y * NW;
    unsigned short* blob = ws + ((size_t)bid << 14);
    int tid = threadIdx.x, xp = tid & 31, cg = tid >> 5;
    Stage st;
    stage_issue(st, row, xp, cg);
    stage_commit_glob(st, blob, xp, cg);
}

// ---------------- main kernel ----------------
struct BStage { u32x4 q[4]; };   // 64 B/thread: one 32 KB blob across 512 threads

__device__ __forceinline__ void bstage_issue(BStage& st, const unsigned short* blob, int tid) {
    const u32x4* p = reinterpret_cast<const u32x4*>(blob) + tid;
    st.q[0] = p[0]; st.q[1] = p[512]; st.q[2] = p[1024]; st.q[3] = p[1536];
}
__device__ __forceinline__ void bstage_commit(const BStage& st, unsigned short* lds, int tid) {
    u32x4* p = reinterpret_cast<u32x4*>(lds) + tid;
    p[0] = st.q[0]; p[512] = st.q[1]; p[1024] = st.q[2]; p[1536] = st.q[3];
}

__global__ __launch_bounds__(512, 4) void corr_main(const float* __restrict__ f1,
                                                    const unsigned short* __restrict__ ws,
                                                    float* __restrict__ out) {
    __shared__ __align__(16) unsigned short buf0[16384];   // 32 KB
    __shared__ __align__(16) unsigned short buf1[16384];   // 32 KB
    __shared__ float Slds[64][33];

    int bid = blockIdx.x;
    // bijective XCD swizzle: 768 = 8*96; hf pairs adjacent, uy consecutive per XCD
    int swz = (bid & 7) * 96 + (bid >> 3);
    int hf  = swz & 1;
    int uy  = (swz >> 1) % 24;
    int g   = swz / 48;            // b*2 + py
    int py  = g & 1;
    int b   = g >> 1;
    int y   = 2 * uy + py;

    int tid = threadIdx.x, lane = tid & 63, w = tid >> 6;
    int xp = tid & 31, cg = tid >> 5;

    const float* f1row = f1 + (size_t)b * NC * HW + (size_t)y * NW;
    float* outb = out + (size_t)b * 441 * HW + (size_t)y * NW;   // + d*HW + x

    int ilo_h = hf ? 11 : 0;
    int ihi_h = hf ? 20 : 10;
    int ilo   = imax(ilo_h, 10 - uy);
    int ihi   = imin(ihi_h, 33 - uy);

    for (int i = ilo_h; i <= ihi_h; ++i) {          // zero-fill invalid rows
        if (i >= ilo && i <= ihi) continue;
        for (int t = tid; t < ND * 64; t += 512) {
            int j = t >> 6, x = t & 63;
            outb[(size_t)(i * ND + j) * HW + x] = 0.f;
        }
    }
    if (ilo > ihi) return;

    // ---- prologue: stage A (f32 -> bf16) into buf0, hoist fragments ----
    Stage ast;
    stage_issue(ast, f1row, xp, cg);
    BStage bst;   // issue first B row early (linear blob copy)
    bstage_issue(bst, ws + ((size_t)(b * 48 + 2 * (uy + ilo - 10) + py) << 14), tid);
    stage_commit_lds(ast, buf0, xp, cg);
    BARRIER();                                       // A ready

    int px  = w & 1;
    int m0  = ((w >> 1) & 1) * 16;
    int n0  = ((w >> 2) & 1) * 16;
    int l15 = lane & 15;
    int kgr = (lane >> 4) * 8;

    short8 afrag[8];
    int arow = 2 * (m0 + l15) + px;
    #pragma unroll
    for (int kk = 0; kk < 8; ++kk)
        afrag[kk] = *reinterpret_cast<const short8*>(
            reinterpret_cast<const char*>(buf0) + swz_off(arow, kk * 32 + kgr));
    BARRIER();                                       // hoists done; buf0 reusable

    int brow = 2 * (n0 + l15) + px;
    int srow = 2 * (m0 + (lane >> 4) * 4) + px;
    int scol = n0 + l15;

    for (int i = ilo; i <= ihi; ++i) {
        unsigned short* cur = ((i - ilo) & 1) ? buf0 : buf1;
        bstage_commit(bst, cur, tid);                // write-late (waits its own loads only)
        if (i < ihi)                                  // issue-early for next row
            bstage_issue(bst, ws + ((size_t)(b * 48 + 2 * (uy + i + 1 - 10) + py) << 14), tid);
        BARRIER();                                   // cur ready for all waves

        f32x4 acc = {0.f, 0.f, 0.f, 0.f};
        #pragma unroll
        for (int kk = 0; kk < 8; ++kk) {
            short8 bfrag = *reinterpret_cast<const short8*>(
                reinterpret_cast<const char*>(cur) + swz_off(brow, kk * 32 + kgr));
            acc = __builtin_amdgcn_mfma_f32_16x16x32_bf16(afrag[kk], bfrag, acc, 0, 0, 0);
        }
        #pragma unroll
        for (int r = 0; r < 4; ++r)                  // C/D: col=lane&15 -> vx, row -> ux
            Slds[srow + 2 * r][scol] = acc[r] * (1.f / 256.f);
        BARRIER();                                   // S ready; cur fully consumed

        for (int t = tid; t < ND * 64; t += 512) {   // banded gather, 256 B stores
            int j = t >> 6, x = t & 63;
            int vx = (x >> 1) + j - 10;
            float v = ((unsigned)vx < 32u) ? Slds[x][vx] : 0.f;
            outb[(size_t)(i * ND + j) * HW + x] = v;
        }
    }
}

// ---------------- fallback (round-1 structure, known good) ----------------
__global__ __launch_bounds__(512, 4) void corr_fallback(const float* __restrict__ f1,
                                                        const float* __restrict__ f2,
                                                        float* __restrict__ out) {
    __shared__ __align__(16) unsigned short Alds[64 * 256];
    __shared__ __align__(16) unsigned short Blds[64 * 256];
    __shared__ float Slds[64][33];

    int bid = blockIdx.x;
    int swz = (bid & 7) * 48 + (bid >> 3);
    int uy = swz % 24;
    int g  = swz / 24;
    int py = g & 1;
    int b  = g >> 1;
    int y  = 2 * uy + py;

    int tid = threadIdx.x, lane = tid & 63, w = tid >> 6;
    int xp = tid & 31, cg = tid >> 5;

    const float* f1row  = f1 + (size_t)b * NC * HW + (size_t)y * NW;
    const float* f2base = f2 + (size_t)b * NC * HW;
    float* outb = out + (size_t)b * 441 * HW + (size_t)y * NW;

    for (int i = 0; i < ND; ++i) {
        int vy = uy + i - 10;
        if (vy >= 0 && vy < 24) continue;
        for (int t = tid; t < ND * 64; t += 512) {
            int j = t >> 6, x = t & 63;
            outb[(size_t)(i * ND + j) * HW + x] = 0.f;
        }
    }

    Stage st;
    stage_issue(st, f1row, xp, cg);
    stage_commit_lds(st, Alds, xp, cg);
    __syncthreads();

    int px  = w & 1;
    int m0  = ((w >> 1) & 1) * 16;
    int n0  = ((w >> 2) & 1) * 16;
    int l15 = lane & 15;
    int kgr = (lane >> 4) * 8;

    short8 afrag[8];
    int arow = 2 * (m0 + l15) + px;
    #pragma unroll
    for (int kk = 0; kk < 8; ++kk)
        afrag[kk] = *reinterpret_cast<const short8*>(
            reinterpret_cast<const char*>(Alds) + swz_off(arow, kk * 32 + kgr));

    int brow = 2 * (n0 + l15) + px;
    int srow = 2 * (m0 + (lane >> 4) * 4) + px;
    int scol = n0 + l15;

    for (int vy = uy - 10; vy <= uy + 10; ++vy) {
        if (vy < 0 || vy >= 24) continue;
        int i  = vy - uy + 10;
        int y2 = 2 * vy + py;
        __syncthreads();
        stage_issue(st, f2base + (size_t)y2 * NW, xp, cg);
        stage_commit_lds(st, Blds, xp, cg);
        __syncthreads();

        f32x4 acc = {0.f, 0.f, 0.f, 0.f};
        #pragma unroll
        for (int kk = 0; kk < 8; ++kk) {
            short8 bfrag = *reinterpret_cast<const short8*>(
                reinterpret_cast<const char*>(Blds) + swz_off(brow, kk * 32 + kgr));
            acc = __builtin_amdgcn_mfma_f32_16x16x32_bf16(afrag[kk], bfrag, acc, 0, 0, 0);
        }
        #pragma unroll
        for (int r = 0; r < 4; ++r)
            Slds[srow + 2 * r][scol] = acc[r] * (1.f / 256.f);
        __syncthreads();

        for (int t = tid; t < ND * 64; t += 512) {
            int j = t >> 6, x = t & 63;
            int vx = (x >> 1) + j - 10;
            float v = ((unsigned)vx < 32u) ? Slds[x][vx] : 0.f;
            outb[(size_t)(i * ND + j) * HW + x] = v;
        }
    }
}

extern "C" void kernel_launch(void* const* d_in, const int* in_sizes, int n_in,
                              void* d_out, int out_size, void* d_ws, size_t ws_size,
                              hipStream_t stream) {
    const float* in1 = (const float*)d_in[0];
    const float* in2 = (const float*)d_in[1];
    float* o = (float*)d_out;
    if (ws_size >= WS_NEEDED) {
        hipLaunchKernelGGL(prep_kernel, dim3(384), dim3(512), 0, stream, in2, (unsigned short*)d_ws);
        hipLaunchKernelGGL(corr_main, dim3(768), dim3(512), 0, stream, in1, (const unsigned short*)d_ws, o);
    } else {
        hipLaunchKernelGGL(corr_fallback, dim3(384), dim3(512), 0, stream, in1, in2, o);
    }
}

// Round 4
// 43.354 us; speedup vs baseline: 1.9518x; 1.0332x over previous
//
#include <hip/hip_runtime.h>

using short8 = __attribute__((ext_vector_type(8))) short;
using f32x4  = __attribute__((ext_vector_type(4))) float;
using u32x4  = __attribute__((ext_vector_type(4))) unsigned int;

#define NC 256
#define NW 64
#define ND 21
#define HW 3072              /* 48*64, per-channel stride in floats */
#define H2 24

static const size_t WS_F2   = (size_t)384 * 32 * 1024;   /* f2 blobs only  */
static const size_t WS_FULL = (size_t)768 * 32 * 1024;   /* f2 + f1 blobs  */

__device__ __forceinline__ int imax(int a, int b) { return a > b ? a : b; }
__device__ __forceinline__ int imin(int a, int b) { return a < b ? a : b; }

__device__ __forceinline__ unsigned int cvtpk(float a, float b) {
    unsigned int r;
    asm("v_cvt_pk_bf16_f32 %0, %1, %2" : "=v"(r) : "v"(a), "v"(b));
    return r;
}

// byte offset into a [64 rows][256 ch] bf16 tile, XOR-swizzled (verified R1-R3)
__device__ __forceinline__ unsigned int swz_off(int row, int cb) {
    return (row << 9) + ((cb << 1) ^ (((row >> 1) & 7) << 4));
}

// barrier draining LDS ops only — global loads stay in flight
#define BARRIER() asm volatile("s_waitcnt lgkmcnt(0)\n\ts_barrier" ::: "memory")

struct Stage { float2 v[16]; };   // one f32 row slice: 128 B/thread

__device__ __forceinline__ void stage_issue(Stage& st, const float* rowbase, int xp, int cg) {
    const float* s = rowbase + 2 * xp;
    #pragma unroll
    for (int cc = 0; cc < 2; ++cc)
        #pragma unroll
        for (int e = 0; e < 4; ++e) {
            int c = cc * 128 + cg * 8 + 2 * e;
            st.v[cc * 8 + 2 * e    ] = *reinterpret_cast<const float2*>(s + (size_t)c * HW);
            st.v[cc * 8 + 2 * e + 1] = *reinterpret_cast<const float2*>(s + (size_t)(c + 1) * HW);
        }
}

__device__ __forceinline__ void stage_pack(const Stage& st, int cc, u32x4& p0, u32x4& p1) {
    #pragma unroll
    for (int e = 0; e < 4; ++e) {
        float2 va = st.v[cc * 8 + 2 * e];
        float2 vb = st.v[cc * 8 + 2 * e + 1];
        p0[e] = cvtpk(va.x, vb.x);
        p1[e] = cvtpk(va.y, vb.y);
    }
}

__device__ __forceinline__ void stage_commit_lds(const Stage& st, unsigned short* lds, int xp, int cg) {
    #pragma unroll
    for (int cc = 0; cc < 2; ++cc) {
        int c0 = cc * 128 + cg * 8;
        u32x4 p0, p1;
        stage_pack(st, cc, p0, p1);
        *reinterpret_cast<u32x4*>(reinterpret_cast<char*>(lds) + swz_off(2 * xp,     c0)) = p0;
        *reinterpret_cast<u32x4*>(reinterpret_cast<char*>(lds) + swz_off(2 * xp + 1, c0)) = p1;
    }
}

__device__ __forceinline__ void stage_commit_glob(const Stage& st, unsigned short* blob, int xp, int cg) {
    #pragma unroll
    for (int cc = 0; cc < 2; ++cc) {
        int c0 = cc * 128 + cg * 8;
        u32x4 p0, p1;
        stage_pack(st, cc, p0, p1);
        *reinterpret_cast<u32x4*>(reinterpret_cast<char*>(blob) + swz_off(2 * xp,     c0)) = p0;
        *reinterpret_cast<u32x4*>(reinterpret_cast<char*>(blob) + swz_off(2 * xp + 1, c0)) = p1;
    }
}

// ---- pre-pass: f32 [c][x] row -> bf16 blob [x][c] swizzled (32 KB each) ----
// grid 384: f2 only (blobs 0..383). grid 768: + f1 (blobs 384..767).
__global__ __launch_bounds__(512, 4) void prep_kernel(const float* __restrict__ f1,
                                                      const float* __restrict__ f2,
                                                      unsigned short* __restrict__ ws) {
    int bid = blockIdx.x;
    const float* src = f2;
    int rid = bid;
    if (bid >= 384) { src = f1; rid = bid - 384; }
    int b = rid / 48, y = rid - b * 48;
    const float* row = src + (size_t)b * NC * HW + (size_t)y * NW;
    unsigned short* blob = ws + ((size_t)bid << 14);
    int tid = threadIdx.x, xp = tid & 31, cg = tid >> 5;
    Stage st;
    stage_issue(st, row, xp, cg);
    stage_commit_glob(st, blob, xp, cg);
}

// ---- linear blob <-> LDS copy: 64 B/thread over 512 threads = 32 KB ----
struct BStage { u32x4 q[4]; };

__device__ __forceinline__ void bstage_issue(BStage& st, const unsigned short* blob, int tid) {
    const u32x4* p = reinterpret_cast<const u32x4*>(blob) + tid;
    st.q[0] = p[0]; st.q[1] = p[512]; st.q[2] = p[1024]; st.q[3] = p[1536];
}
__device__ __forceinline__ void bstage_commit(const BStage& st, unsigned short* lds, int tid) {
    u32x4* p = reinterpret_cast<u32x4*>(lds) + tid;
    p[0] = st.q[0]; p[512] = st.q[1]; p[1024] = st.q[2]; p[1536] = st.q[3];
}

// ---- main kernel: WG = (b, py, uy-pair, hf); 2 y-rows per WG ----
template<bool ABLOB>
__global__ __launch_bounds__(512, 4) void corr_main2(const float* __restrict__ f1,
                                                     const unsigned short* __restrict__ ws,
                                                     float* __restrict__ out) {
    __shared__ __align__(16) unsigned short buf[16384];   // 32 KB: A rows (prologue), then B row
    __shared__ float Slds[2][64][33];                     // 16.9 KB

    int bid = blockIdx.x;
    // bijective XCD swizzle: 384 = 8*48; one XCD chunk = 2 (b,py) groups
    int swz = (bid & 7) * 48 + (bid >> 3);
    int g    = swz / 24;           // b*2 + py
    int wi   = swz % 24;
    int pair = wi >> 1, hf = wi & 1;
    int uy0  = 2 * pair;
    int py   = g & 1, b = g >> 1;

    int tid = threadIdx.x, lane = tid & 63, w = tid >> 6;
    int px = w & 1, r = (w >> 1) & 1, nh = (w >> 2) & 1;
    int l15 = lane & 15, g4 = lane >> 4;
    int xp = tid & 31, cg = tid >> 5;

    const unsigned short* f2blob = ws;                         // blob (b*48 + y)
    const unsigned short* f1blob = ws + (size_t)384 * 16384;   // blob 384 + (b*48 + y)

    int ilo_h = hf ? 11 : 0, ihi_h = hf ? 20 : 10;

    float* outb0 = out + (size_t)b * 441 * HW + (size_t)(2 * uy0 + py) * NW;
    float* outb1 = outb0 + 2 * NW;    // row y+2

    // zero-fill output rows whose displaced source row is out of bounds
    #pragma unroll
    for (int rr = 0; rr < 2; ++rr) {
        float* ob = rr ? outb1 : outb0;
        for (int i = ilo_h; i <= ihi_h; ++i) {
            int vy = uy0 + rr + i - 10;
            if ((unsigned)vy < (unsigned)H2) continue;
            for (int t = tid; t < ND * 64; t += 512) {
                int j = t >> 6, x = t & 63;
                ob[(size_t)(i * ND + j) * HW + x] = 0.f;
            }
        }
    }

    // vy range needed by this (pair, hf): union over the 2 rows
    int vlo = hf ? (uy0 + 1) : imax(0, uy0 - 10);
    int vhi = hf ? imin(H2 - 1, uy0 + 11) : (uy0 + 1);

    short8 afrag[2][8];
    auto hoist = [&]() {
        #pragma unroll
        for (int m = 0; m < 2; ++m)
            #pragma unroll
            for (int kk = 0; kk < 8; ++kk)
                afrag[m][kk] = *reinterpret_cast<const short8*>(
                    reinterpret_cast<const char*>(buf) + swz_off(2 * (m * 16 + l15) + px, kk * 32 + g4 * 8));
    };

    BStage bst;
    // ---- prologue: stage the two A rows through buf, hoist per-wave fragments ----
    if (ABLOB) {
        BStage a0, a1;
        bstage_issue(a0, f1blob + ((size_t)(b * 48 + 2 * uy0 + py) << 14), tid);
        bstage_issue(a1, f1blob + ((size_t)(b * 48 + 2 * uy0 + 2 + py) << 14), tid);
        bstage_commit(a0, buf, tid);
        BARRIER();                       // A row0 ready
        if (r == 0) hoist();
        BARRIER();                       // row0 reads done
        bstage_commit(a1, buf, tid);
        BARRIER();                       // A row1 ready
        if (r == 1) hoist();
    } else {
        Stage s;
        stage_issue(s, f1 + (size_t)b * NC * HW + (size_t)(2 * uy0 + py) * NW, xp, cg);
        stage_commit_lds(s, buf, xp, cg);
        BARRIER();
        if (r == 0) hoist();
        BARRIER();
        stage_issue(s, f1 + (size_t)b * NC * HW + (size_t)(2 * uy0 + 2 + py) * NW, xp, cg);
        stage_commit_lds(s, buf, xp, cg);
        BARRIER();
        if (r == 1) hoist();
    }
    bstage_issue(bst, f2blob + ((size_t)(b * 48 + 2 * vlo + py) << 14), tid);
    BARRIER();                           // A reads done before first B commit

    int brow = 2 * (nh * 16 + l15) + px;

    for (int vy = vlo; vy <= vhi; ++vy) {
        bstage_commit(bst, buf, tid);    // write-late (waits only its own loads)
        if (vy < vhi)
            bstage_issue(bst, f2blob + ((size_t)(b * 48 + 2 * (vy + 1) + py) << 14), tid);
        BARRIER();   // buf ready; also orders prev gather before this iter's S write

        f32x4 acc0 = {0.f, 0.f, 0.f, 0.f};
        f32x4 acc1 = {0.f, 0.f, 0.f, 0.f};
        #pragma unroll
        for (int kk = 0; kk < 8; ++kk) {
            short8 bf = *reinterpret_cast<const short8*>(
                reinterpret_cast<const char*>(buf) + swz_off(brow, kk * 32 + g4 * 8));
            acc0 = __builtin_amdgcn_mfma_f32_16x16x32_bf16(afrag[0][kk], bf, acc0, 0, 0, 0);
            acc1 = __builtin_amdgcn_mfma_f32_16x16x32_bf16(afrag[1][kk], bf, acc1, 0, 0, 0);
        }
        // C/D: col = lane&15 -> vx, row = g4*4 + rr -> ux (verified R1-R3)
        #pragma unroll
        for (int rr = 0; rr < 4; ++rr) {
            Slds[r][2 * (     g4 * 4 + rr) + px][nh * 16 + l15] = acc0[rr] * (1.f / 256.f);
            Slds[r][2 * (16 + g4 * 4 + rr) + px][nh * 16 + l15] = acc1[rr] * (1.f / 256.f);
        }
        BARRIER();   // S ready; B-frag reads retired

        // banded gather for each row this vy serves; coalesced 256 B stores
        #pragma unroll
        for (int rr = 0; rr < 2; ++rr) {
            int i = vy - uy0 - rr + 10;
            if (i < ilo_h || i > ihi_h) continue;
            float* ob = rr ? outb1 : outb0;
            for (int t = tid; t < ND * 64; t += 512) {
                int j = t >> 6, x = t & 63;
                int vx = (x >> 1) + j - 10;
                float v = ((unsigned)vx < 32u) ? Slds[rr][x][vx] : 0.f;
                ob[(size_t)(i * ND + j) * HW + x] = v;
            }
        }
    }
}

// ---- fallback (round-1 structure, known good, no workspace) ----
__global__ __launch_bounds__(512, 4) void corr_fallback(const float* __restrict__ f1,
                                                        const float* __restrict__ f2,
                                                        float* __restrict__ out) {
    __shared__ __align__(16) unsigned short Alds[64 * 256];
    __shared__ __align__(16) unsigned short Blds[64 * 256];
    __shared__ float Slds[64][33];

    int bid = blockIdx.x;
    int swz = (bid & 7) * 48 + (bid >> 3);
    int uy = swz % 24;
    int g  = swz / 24;
    int py = g & 1;
    int b  = g >> 1;
    int y  = 2 * uy + py;

    int tid = threadIdx.x, lane = tid & 63, w = tid >> 6;
    int xp = tid & 31, cg = tid >> 5;

    const float* f1row  = f1 + (size_t)b * NC * HW + (size_t)y * NW;
    const float* f2base = f2 + (size_t)b * NC * HW;
    float* outb = out + (size_t)b * 441 * HW + (size_t)y * NW;

    for (int i = 0; i < ND; ++i) {
        int vy = uy + i - 10;
        if (vy >= 0 && vy < H2) continue;
        for (int t = tid; t < ND * 64; t += 512) {
            int j = t >> 6, x = t & 63;
            outb[(size_t)(i * ND + j) * HW + x] = 0.f;
        }
    }

    Stage st;
    stage_issue(st, f1row, xp, cg);
    stage_commit_lds(st, Alds, xp, cg);
    __syncthreads();

    int px  = w & 1;
    int m0  = ((w >> 1) & 1) * 16;
    int n0  = ((w >> 2) & 1) * 16;
    int l15 = lane & 15;
    int kgr = (lane >> 4) * 8;

    short8 afrag[8];
    int arow = 2 * (m0 + l15) + px;
    #pragma unroll
    for (int kk = 0; kk < 8; ++kk)
        afrag[kk] = *reinterpret_cast<const short8*>(
            reinterpret_cast<const char*>(Alds) + swz_off(arow, kk * 32 + kgr));

    int brow = 2 * (n0 + l15) + px;
    int srow = 2 * (m0 + (lane >> 4) * 4) + px;
    int scol = n0 + l15;

    for (int vy = uy - 10; vy <= uy + 10; ++vy) {
        if (vy < 0 || vy >= H2) continue;
        int i  = vy - uy + 10;
        int y2 = 2 * vy + py;
        __syncthreads();
        stage_issue(st, f2base + (size_t)y2 * NW, xp, cg);
        stage_commit_lds(st, Blds, xp, cg);
        __syncthreads();

        f32x4 acc = {0.f, 0.f, 0.f, 0.f};
        #pragma unroll
        for (int kk = 0; kk < 8; ++kk) {
            short8 bfrag = *reinterpret_cast<const short8*>(
                reinterpret_cast<const char*>(Blds) + swz_off(brow, kk * 32 + kgr));
            acc = __builtin_amdgcn_mfma_f32_16x16x32_bf16(afrag[kk], bfrag, acc, 0, 0, 0);
        }
        #pragma unroll
        for (int r = 0; r < 4; ++r)
            Slds[srow + 2 * r][scol] = acc[r] * (1.f / 256.f);
        __syncthreads();

        for (int t = tid; t < ND * 64; t += 512) {
            int j = t >> 6, x = t & 63;
            int vx = (x >> 1) + j - 10;
            float v = ((unsigned)vx < 32u) ? Slds[x][vx] : 0.f;
            outb[(size_t)(i * ND + j) * HW + x] = v;
        }
    }
}

extern "C" void kernel_launch(void* const* d_in, const int* in_sizes, int n_in,
                              void* d_out, int out_size, void* d_ws, size_t ws_size,
                              hipStream_t stream) {
    const float* in1 = (const float*)d_in[0];
    const float* in2 = (const float*)d_in[1];
    float* o = (float*)d_out;
    if (ws_size >= WS_FULL) {
        hipLaunchKernelGGL(prep_kernel, dim3(768), dim3(512), 0, stream, in1, in2, (unsigned short*)d_ws);
        hipLaunchKernelGGL(corr_main2<true>, dim3(384), dim3(512), 0, stream,
                           in1, (const unsigned short*)d_ws, o);
    } else if (ws_size >= WS_F2) {
        hipLaunchKernelGGL(prep_kernel, dim3(384), dim3(512), 0, stream, in1, in2, (unsigned short*)d_ws);
        hipLaunchKernelGGL(corr_main2<false>, dim3(384), dim3(512), 0, stream,
                           in1, (const unsigned short*)d_ws, o);
    } else {
        hipLaunchKernelGGL(corr_fallback, dim3(384), dim3(512), 0, stream, in1, in2, o);
    }
}